// Round 7
// baseline (892.859 us; speedup 1.0000x reference)
//
#include <hip/hip_runtime.h>
#include <hip/hip_bf16.h>
#include <cstdint>
#include <cstddef>

using bf16 = __hip_bfloat16;
typedef __attribute__((ext_vector_type(8))) short short8;
typedef __attribute__((ext_vector_type(4))) float f32x4;

// ---------------------------------------------------------------------------
// Exact posit(16, es=1) round-trip quantization (round-1 derivation).
// ---------------------------------------------------------------------------
__device__ __forceinline__ float posit_quant_f32(float x) {
  float absx = fabsf(x);
  float safe = fmaxf(absx, 1e-30f);
  uint32_t bits = __float_as_uint(safe);
  int scale = (int)((bits >> 23) & 0xFFu) - 127;
  int regime = scale >> 1;
  int rlen = (regime >= 0) ? (regime + 2) : (1 - regime);
  int fbits = 14 - rlen;
  fbits = fbits < 0 ? 0 : fbits;
  float pw = (float)(1 << fbits);
  float m = __uint_as_float((bits & 0x007FFFFFu) | 0x3F800000u);
  float mq = rintf((m - 1.0f) * pw) * (1.0f / pw) + 1.0f;
  float mag = mq * __uint_as_float((uint32_t)(scale + 127) << 23);
  mag = fminf(fmaxf(mag, 0x1p-28f), 0x1p28f);
  return (absx == 0.0f) ? 0.0f : copysignf(mag, x);
}

__device__ __forceinline__ ushort4 pq_bf16x4(float4 v) {
  ushort4 o;
  o.x = __builtin_bit_cast(unsigned short, __float2bfloat16(posit_quant_f32(v.x)));
  o.y = __builtin_bit_cast(unsigned short, __float2bfloat16(posit_quant_f32(v.y)));
  o.z = __builtin_bit_cast(unsigned short, __float2bfloat16(posit_quant_f32(v.z)));
  o.w = __builtin_bit_cast(unsigned short, __float2bfloat16(posit_quant_f32(v.w)));
  return o;
}

// One launch quantizing all four f32 arrays -> posit -> bf16 (float4-wide).
__global__ void kquant_all(const float* __restrict__ s0, bf16* __restrict__ d0,
                           const float* __restrict__ s1, bf16* __restrict__ d1,
                           const float* __restrict__ s2, bf16* __restrict__ d2,
                           const float* __restrict__ s3, bf16* __restrict__ d3,
                           long c0, long c1, long c2, long c3) {
  long i = (long)blockIdx.x * blockDim.x + threadIdx.x;
  long stride = (long)gridDim.x * blockDim.x;
  for (; i < c3; i += stride) {
    const float* s; bf16* d; long j;
    if (i < c0)      { s = s0; d = d0; j = i; }
    else if (i < c1) { s = s1; d = d1; j = i - c0; }
    else if (i < c2) { s = s2; d = d2; j = i - c1; }
    else             { s = s3; d = d3; j = i - c2; }
    float4 v = ((const float4*)s)[j];
    ((ushort4*)d)[j] = pq_bf16x4(v);
  }
}

// combine split-K partials: out = pq(p0 + p1 + pq(bias))
__global__ void kcombine(const float* __restrict__ p, const float* __restrict__ bias,
                         float* __restrict__ out, long n4, long halfn, int cmask) {
  long i = (long)blockIdx.x * blockDim.x + threadIdx.x;
  long stride = (long)gridDim.x * blockDim.x;
  for (; i < n4; i += stride) {
    float4 a = ((const float4*)p)[i];
    float4 b = ((const float4*)(p + halfn))[i];
    int c0 = (int)(i & cmask) * 4;
    float4 o;
    o.x = posit_quant_f32(a.x + b.x + posit_quant_f32(bias[c0 + 0]));
    o.y = posit_quant_f32(a.y + b.y + posit_quant_f32(bias[c0 + 1]));
    o.z = posit_quant_f32(a.z + b.z + posit_quant_f32(bias[c0 + 2]));
    o.w = posit_quant_f32(a.w + b.w + posit_quant_f32(bias[c0 + 3]));
    ((float4*)out)[i] = o;
  }
}

typedef __attribute__((address_space(1))) uint32_t gu32;
typedef __attribute__((address_space(3))) uint32_t lu32;

// ===========================================================================
// 256x256 tile, BK=64, 8 waves (2x4), 16x16x32 MFMA.
// MONO-PHASE schedule: 1 barrier + 1 vmcnt(0) per K-tile (vs 8 barriers in
// the 8-phase template). Rationale: 128KB LDS => 1 block/CU, so there is no
// co-resident block to hide per-phase sync overhead; fewer, longer phases
// amortize it. vmcnt(0) is safe: the waited loads were issued a full K-tile
// (~1700cy) earlier, > HBM miss latency. Fragments for the whole K-tile live
// in registers (A 8x + B 8x short8 = 64 VGPR; total ~220 < 256, 2 waves/SIMD).
// Per K-tile t (buf = t&1):
//   VMCNT(0); SBAR();            // tile-t DMA complete (all waves)
//   STG A(t+1) -> other A-buf    // region's readers finished pre-barrier
//   read B(t) 8 + aLo(t) 8; MFMA lo (32)
//   STG B(t+1) -> other B-buf
//   read aHi(t) 8;               MFMA hi (32)
// LDS: A bufs 0/32768, B bufs 65536/98304. Row-major 128 B/row; swizzle
// colbyte ^= ((row&7)<<4); inverse-swizzled global source (both-sides rule).
// MODE: 0 = bias+pq+relu, bf16 out; 1 = bias+pq, f32 out; 2 = raw f32 partial.
// ===========================================================================
#define SBAR()  do { __builtin_amdgcn_sched_barrier(0); __builtin_amdgcn_s_barrier(); \
                     __builtin_amdgcn_sched_barrier(0); } while (0)
#define VMCNT(N) asm volatile("s_waitcnt vmcnt(" #N ")" ::: "memory")

#define AB0 0
#define AB1 32768
#define BB0 65536
#define BB1 98304

// Stage 128 rows (half tile H) of SRC K-tile KT into LDS region DST
#define STG(SRC, KT, H, DST) do { \
    const char* _s = (SRC) + (long)((H) * 128) * Kb + (long)(KT) * 128; \
    char* _d = smem + (DST) + (H) * 16384 + wave * 1024; \
    __builtin_amdgcn_global_load_lds((const gu32*)_s, (lu32*)_d, 16, 0, 0); \
    __builtin_amdgcn_global_load_lds((const gu32*)(_s + 64 * Kb), (lu32*)(_d + 8192), 16, 0, 0); \
  } while (0)

#define LDA8(AOFF, FI, CK) (*(const short8*)(smem + (AOFF) + aRel + (FI) * 2048 + (CK)))
#define LDB8(BOFF, FJ, CK) (*(const short8*)(smem + (BOFF) + bRel + (FJ) * 2048 + (CK)))

// Fragment reads
#define PREF_ALO(BUF) do { _Pragma("unroll") \
    for (int f = 0; f < 4; ++f) { ar[f][0] = LDA8(BUF, f, ck0); ar[f][1] = LDA8(BUF, f, ck1); } \
  } while (0)
#define PREF_AHI(BUF) do { _Pragma("unroll") \
    for (int f = 0; f < 4; ++f) { ar[f][0] = LDA8(BUF, f + 4, ck0); ar[f][1] = LDA8(BUF, f + 4, ck1); } \
  } while (0)
#define PREF_B(BUF) do { _Pragma("unroll") \
    for (int f = 0; f < 4; ++f) { br[f][0] = LDB8(BUF, f, ck0); br[f][1] = LDB8(BUF, f, ck1); } \
  } while (0)

// Half-tile MFMA block: acc rows ACC0..ACC0+3 x all 4 fj (32 MFMA)
#define MQALL(ACC0) do { \
    _Pragma("unroll") \
    for (int fi = 0; fi < 4; ++fi) { \
      _Pragma("unroll") \
      for (int fj = 0; fj < 4; ++fj) { \
        acc[(ACC0) + fi][fj] = __builtin_amdgcn_mfma_f32_16x16x32_bf16( \
            ar[fi][0], br[fj][0], acc[(ACC0) + fi][fj], 0, 0, 0); \
        acc[(ACC0) + fi][fj] = __builtin_amdgcn_mfma_f32_16x16x32_bf16( \
            ar[fi][1], br[fj][1], acc[(ACC0) + fi][fj], 0, 0, 0); \
      } \
    } \
  } while (0)

template <int MODE>
__global__ __launch_bounds__(512, 2) void gemm256_posit(
    const bf16* __restrict__ A, const bf16* __restrict__ B,
    const float* __restrict__ bias, void* __restrict__ out,
    int M, int N, int Kfull, int Kloop, int nbt, int cpx) {
  __shared__ __align__(1024) char smem[131072];

  const int tid  = threadIdx.x;
  const int lane = tid & 63;
  const int wave = tid >> 6;
  const int wr = wave >> 2;         // 0..1  (M half)
  const int wc = wave & 3;          // 0..3  (N quarter)

  // XCD-aware bijective swizzle (grid multiple of 8), then split-K decode
  const int flat = blockIdx.x;
  const int wgid = (flat & 7) * cpx + (flat >> 3);
  const int split = wgid / nbt;               // 0 unless split-K
  const int t = wgid - split * nbt;
  const int nbx = N >> 8;
  const long brow0 = (long)(t / nbx) * 256;
  const long bcol0 = (long)(t % nbx) * 256;

  const long Kb = (long)Kfull * 2;            // row stride bytes
  const long splitoff = (long)split * Kloop * 2;

  // staging source (per-lane, inverse-swizzled)
  const int srow = tid >> 3;                                   // 0..63
  const int scb  = ((tid & 7) * 16) ^ (((tid >> 3) & 7) << 4);
  const char* srcA = (const char*)A + (brow0 + srow) * Kb + scb + splitoff;
  const char* srcB = (const char*)B + (bcol0 + srow) * Kb + scb + splitoff;

  // fragment read addressing (mfma_f32_16x16x32_bf16: row=lane&15, k=(lane>>4)*8)
  const int fr  = lane & 15;
  const int swz = (lane & 7) << 4;
  const int ck0 = (((lane >> 4) << 4)) ^ swz;
  const int ck1 = (64 + ((lane >> 4) << 4)) ^ swz;
  const int aRel = wr * 16384 + fr * 128;
  const int bRel = wc * 8192 + fr * 128;

  f32x4 acc[8][4] = {};
  short8 ar[4][2], br[4][2];

  const int nkt = Kloop >> 6;     // K tiles (power of 2, >= 2)
  const int np  = nkt >> 1;

  // Prologue: stage tile 0 only (8 loads).
  STG(srcA, 0, 0, AB0); STG(srcA, 0, 1, AB0);
  STG(srcB, 0, 0, BB0); STG(srcB, 0, 1, BB0);

#pragma unroll 1
  for (int i = 0; i < np; ++i) {
    const int t1 = (2 * i + 1) & (nkt - 1);
    const int t2 = (2 * i + 2) & (nkt - 1);  // tail wraps: harmless re-stage

    // ---- K-tile 2i (AB0/BB0) ----
    VMCNT(0);                 // tile-2i loads drained (issued a full tile ago)
    SBAR();                   // all waves drained; prev-tile reads finished
    STG(srcA, t1, 0, AB1); STG(srcA, t1, 1, AB1);
    PREF_B(BB0); PREF_ALO(AB0);
    __builtin_amdgcn_s_setprio(1); MQALL(0); __builtin_amdgcn_s_setprio(0);
    STG(srcB, t1, 0, BB1); STG(srcB, t1, 1, BB1);
    PREF_AHI(AB0);
    __builtin_amdgcn_s_setprio(1); MQALL(4); __builtin_amdgcn_s_setprio(0);

    // ---- K-tile 2i+1 (AB1/BB1) ----
    VMCNT(0);
    SBAR();
    STG(srcA, t2, 0, AB0); STG(srcA, t2, 1, AB0);
    PREF_B(BB1); PREF_ALO(AB1);
    __builtin_amdgcn_s_setprio(1); MQALL(0); __builtin_amdgcn_s_setprio(0);
    STG(srcB, t2, 0, BB0); STG(srcB, t2, 1, BB0);
    PREF_AHI(AB1);
    __builtin_amdgcn_s_setprio(1); MQALL(4); __builtin_amdgcn_s_setprio(0);
  }
  asm volatile("s_waitcnt vmcnt(0) lgkmcnt(0)" ::: "memory");  // drain

  // Epilogue: C/D layout col=lane&15, row=(lane>>4)*4+q
  const int orow = (lane >> 4) * 4;
  const long row0 = brow0 + wr * 128;
  const long col0 = bcol0 + wc * 64;
  const long obase = (MODE == 2) ? (long)split * M * N : 0;
#pragma unroll
  for (int fj = 0; fj < 4; ++fj) {
    const long col = col0 + fj * 16 + fr;
    const float bv = (MODE == 2) ? 0.0f : posit_quant_f32(bias[col]);
#pragma unroll
    for (int fi = 0; fi < 8; ++fi) {
#pragma unroll
      for (int q = 0; q < 4; ++q) {
        float v = acc[fi][fj][q];
        if (MODE != 2) {
          v = posit_quant_f32(v + bv);
          if (MODE == 0) v = fmaxf(v, 0.0f);
        }
        const long idx = obase + (row0 + fi * 16 + orow + q) * (long)N + col;
        if (MODE == 0) ((bf16*)out)[idx] = __float2bfloat16(v);
        else           ((float*)out)[idx] = v;
      }
    }
  }
}

// ===========================================================================
// Round-1 128x128 m97-structure kernel (fallback for L2 if ws too small)
// ===========================================================================
#define GBM 128
#define GBN 128
#define GBK 32

__device__ __forceinline__ void gload_lds16(const void* g, void* l) {
  __builtin_amdgcn_global_load_lds((const gu32*)g, (lu32*)l, 16, 0, 0);
}

template <bool RELU, bool OUTBF16>
__global__ __launch_bounds__(256, 2) void gemm_bt_posit(
    const bf16* __restrict__ A, const bf16* __restrict__ B,
    const float* __restrict__ bias, void* __restrict__ out,
    int M, int N, int K) {
  __shared__ __align__(1024) bf16 sA[GBM][GBK];
  __shared__ __align__(1024) bf16 sB[GBN][GBK];

  const int tid = threadIdx.x;
  const int lane = tid & 63;
  const int wave = tid >> 6;
  const int wr = wave >> 1;
  const int wc = wave & 1;
  const long brow0 = (long)blockIdx.y * GBM;
  const long bcol0 = (long)blockIdx.x * GBN;

  const int srow = lane >> 2;
  const int scol = (lane & 3) * 8;
  const int seg0 = wave * 2;

  const bf16* gA0 = A + (brow0 + seg0 * 16 + srow) * (long)K + scol;
  const bf16* gA1 = A + (brow0 + seg0 * 16 + 16 + srow) * (long)K + scol;
  const bf16* gB0 = B + (bcol0 + seg0 * 16 + srow) * (long)K + scol;
  const bf16* gB1 = B + (bcol0 + seg0 * 16 + 16 + srow) * (long)K + scol;
  bf16* lA0 = (bf16*)sA + seg0 * 512;
  bf16* lA1 = lA0 + 512;
  bf16* lB0 = (bf16*)sB + seg0 * 512;
  bf16* lB1 = lB0 + 512;

  f32x4 acc[4][4] = {};
  const int fr = lane & 15;
  const int fk = (lane >> 4) * 8;

  for (int kt = 0; kt < K; kt += GBK) {
    __syncthreads();
    gload_lds16(gA0 + kt, lA0);
    gload_lds16(gA1 + kt, lA1);
    gload_lds16(gB0 + kt, lB0);
    gload_lds16(gB1 + kt, lB1);
    __syncthreads();

    short8 af[4], bfv[4];
#pragma unroll
    for (int i = 0; i < 4; ++i) af[i] = *(const short8*)&sA[wr * 64 + i * 16 + fr][fk];
#pragma unroll
    for (int j = 0; j < 4; ++j) bfv[j] = *(const short8*)&sB[wc * 64 + j * 16 + fr][fk];
#pragma unroll
    for (int i = 0; i < 4; ++i)
#pragma unroll
      for (int j = 0; j < 4; ++j)
        acc[i][j] = __builtin_amdgcn_mfma_f32_16x16x32_bf16(af[i], bfv[j], acc[i][j], 0, 0, 0);
  }

  const int orow = (lane >> 4) * 4;
  const long row0 = brow0 + wr * 64;
  const long col0 = bcol0 + wc * 64;
#pragma unroll
  for (int j = 0; j < 4; ++j) {
    const long col = col0 + j * 16 + fr;
    const float bv = posit_quant_f32(bias[col]);
#pragma unroll
    for (int i = 0; i < 4; ++i) {
#pragma unroll
      for (int q = 0; q < 4; ++q) {
        float v = posit_quant_f32(acc[i][j][q] + bv);
        if (RELU) v = fmaxf(v, 0.0f);
        const long idx = (row0 + i * 16 + orow + q) * (long)N + col;
        if (OUTBF16) ((bf16*)out)[idx] = __float2bfloat16(v);
        else         ((float*)out)[idx] = v;
      }
    }
  }
}

// ---------------------------------------------------------------------------
extern "C" void kernel_launch(void* const* d_in, const int* in_sizes, int n_in,
                              void* d_out, int out_size, void* d_ws, size_t ws_size,
                              hipStream_t stream) {
  const float* x  = (const float*)d_in[0];
  const float* W0 = (const float*)d_in[1];
  const float* b0 = (const float*)d_in[2];
  const float* W1 = (const float*)d_in[3];
  const float* b1 = (const float*)d_in[4];
  const float* W2 = (const float*)d_in[5];
  const float* b2 = (const float*)d_in[6];

  const int M = 4096, D0 = 2048, D1 = 8192, D2 = 8192, DO = 2048;

  char* ws = (char*)d_ws;
  size_t off = 0;
  auto alloc = [&](size_t bytes) {
    char* p = ws + off;
    off += (bytes + 255) & ~(size_t)255;
    return p;
  };
  bf16* xq  = (bf16*)alloc((size_t)M * D0 * 2);
  bf16* W0q = (bf16*)alloc((size_t)D1 * D0 * 2);
  bf16* W1q = (bf16*)alloc((size_t)D2 * D1 * 2);
  bf16* W2q = (bf16*)alloc((size_t)DO * D2 * 2);
  bf16* h0  = (bf16*)alloc((size_t)M * D1 * 2);
  bf16* h1  = (bf16*)alloc((size_t)M * D2 * 2);
  float* part = (float*)alloc((size_t)2 * M * DO * 4);   // split-K partials
  const bool splitk = (off <= ws_size);
  (void)in_sizes; (void)n_in; (void)out_size;

  // Single launch quantizing x, W0, W1, W2 -> bf16 posit values
  {
    long q0 = (long)M * D0 / 4;
    long q1 = q0 + (long)D1 * D0 / 4;
    long q2 = q1 + (long)D2 * D1 / 4;
    long q3 = q2 + (long)DO * D2 / 4;
    kquant_all<<<2048, 256, 0, stream>>>(x, xq, W0, W0q, W1, W1q, W2, W2q,
                                         q0, q1, q2, q3);
  }

  // L0: h0 = relu(pq(xq @ W0q^T + pq(b0)))   M=4096 N=8192 K=2048
  {
    int nbt = (D1 / 256) * (M / 256), nwg = nbt;
    gemm256_posit<0><<<dim3(nwg), dim3(512), 0, stream>>>(
        xq, W0q, b0, h0, M, D1, D0, D0, nbt, nwg / 8);
  }
  // L1: h1 = relu(pq(h0 @ W1q^T + pq(b1)))   M=4096 N=8192 K=8192
  {
    int nbt = (D2 / 256) * (M / 256), nwg = nbt;
    gemm256_posit<0><<<dim3(nwg), dim3(512), 0, stream>>>(
        h0, W1q, b1, h1, M, D2, D1, D1, nbt, nwg / 8);
  }
  // L2: out = pq(h1 @ W2q^T + pq(b2))  f32   M=4096 N=2048 K=8192
  if (splitk) {
    int nbt = (DO / 256) * (M / 256);      // 128 tiles per split
    int nwg = nbt * 2;                     // 256 blocks, full occupancy
    gemm256_posit<2><<<dim3(nwg), dim3(512), 0, stream>>>(
        h1, W2q, nullptr, part, M, DO, D2, D2 / 2, nbt, nwg / 8);
    long n4 = (long)M * DO / 4;
    kcombine<<<2048, 256, 0, stream>>>(part, b2, (float*)d_out, n4,
                                       (long)M * DO, DO / 4 - 1);
  } else {
    gemm_bt_posit<false, false><<<dim3(DO / GBN, M / GBM), dim3(256), 0, stream>>>(
        h1, W2q, b2, (float*)d_out, M, DO, D2);
  }
}

// Round 8
// 852.464 us; speedup vs baseline: 1.0474x; 1.0474x over previous
//
#include <hip/hip_runtime.h>
#include <hip/hip_bf16.h>
#include <cstdint>
#include <cstddef>

using bf16 = __hip_bfloat16;
typedef __attribute__((ext_vector_type(8))) short short8;
typedef __attribute__((ext_vector_type(4))) float f32x4;

// ---------------------------------------------------------------------------
// Exact posit(16, es=1) round-trip quantization (round-1 derivation).
// ---------------------------------------------------------------------------
__device__ __forceinline__ float posit_quant_f32(float x) {
  float absx = fabsf(x);
  float safe = fmaxf(absx, 1e-30f);
  uint32_t bits = __float_as_uint(safe);
  int scale = (int)((bits >> 23) & 0xFFu) - 127;
  int regime = scale >> 1;
  int rlen = (regime >= 0) ? (regime + 2) : (1 - regime);
  int fbits = 14 - rlen;
  fbits = fbits < 0 ? 0 : fbits;
  float pw = (float)(1 << fbits);
  float m = __uint_as_float((bits & 0x007FFFFFu) | 0x3F800000u);
  float mq = rintf((m - 1.0f) * pw) * (1.0f / pw) + 1.0f;
  float mag = mq * __uint_as_float((uint32_t)(scale + 127) << 23);
  mag = fminf(fmaxf(mag, 0x1p-28f), 0x1p28f);
  return (absx == 0.0f) ? 0.0f : copysignf(mag, x);
}

__device__ __forceinline__ ushort4 pq_bf16x4(float4 v) {
  ushort4 o;
  o.x = __builtin_bit_cast(unsigned short, __float2bfloat16(posit_quant_f32(v.x)));
  o.y = __builtin_bit_cast(unsigned short, __float2bfloat16(posit_quant_f32(v.y)));
  o.z = __builtin_bit_cast(unsigned short, __float2bfloat16(posit_quant_f32(v.z)));
  o.w = __builtin_bit_cast(unsigned short, __float2bfloat16(posit_quant_f32(v.w)));
  return o;
}

// One launch quantizing all four f32 arrays -> posit -> bf16 (float4-wide).
__global__ void kquant_all(const float* __restrict__ s0, bf16* __restrict__ d0,
                           const float* __restrict__ s1, bf16* __restrict__ d1,
                           const float* __restrict__ s2, bf16* __restrict__ d2,
                           const float* __restrict__ s3, bf16* __restrict__ d3,
                           long c0, long c1, long c2, long c3) {
  long i = (long)blockIdx.x * blockDim.x + threadIdx.x;
  long stride = (long)gridDim.x * blockDim.x;
  for (; i < c3; i += stride) {
    const float* s; bf16* d; long j;
    if (i < c0)      { s = s0; d = d0; j = i; }
    else if (i < c1) { s = s1; d = d1; j = i - c0; }
    else if (i < c2) { s = s2; d = d2; j = i - c1; }
    else             { s = s3; d = d3; j = i - c2; }
    float4 v = ((const float4*)s)[j];
    ((ushort4*)d)[j] = pq_bf16x4(v);
  }
}

// combine split-K partials: out = pq(p0 + p1 + pq(bias))
__global__ void kcombine(const float* __restrict__ p, const float* __restrict__ bias,
                         float* __restrict__ out, long n4, long halfn, int cmask) {
  long i = (long)blockIdx.x * blockDim.x + threadIdx.x;
  long stride = (long)gridDim.x * blockDim.x;
  for (; i < n4; i += stride) {
    float4 a = ((const float4*)p)[i];
    float4 b = ((const float4*)(p + halfn))[i];
    int c0 = (int)(i & cmask) * 4;
    float4 o;
    o.x = posit_quant_f32(a.x + b.x + posit_quant_f32(bias[c0 + 0]));
    o.y = posit_quant_f32(a.y + b.y + posit_quant_f32(bias[c0 + 1]));
    o.z = posit_quant_f32(a.z + b.z + posit_quant_f32(bias[c0 + 2]));
    o.w = posit_quant_f32(a.w + b.w + posit_quant_f32(bias[c0 + 3]));
    ((float4*)out)[i] = o;
  }
}

typedef __attribute__((address_space(1))) uint32_t gu32;
typedef __attribute__((address_space(3))) uint32_t lu32;

// ===========================================================================
// 256x256 tile, BK=64, 8 waves (2x4), 8-phase schedule, 16x16x32 MFMA,
// scheme-D fragment prefetch (round-6 proven best: L1 ~456us, MfmaUtil 55.5).
// NEW (round 8): 2D BAND tile decode -- each XCD's contiguous wgid chunk is
// a 16-row x 4-col band: row=(t&63)>>2, col=((t>>6)<<2)|(t&3). Consecutive
// same-XCD tiles share the A-panel (4x) and the band's co-resident blocks
// share B K-slices through the XCD's L2 (~16x) instead of streaming the
// whole B-panel from HBM per tile. Expected L1 fetch 1.1GB -> ~0.65GB.
// LDS: A bufs 0/32768, B bufs 65536/98304. Row-major 128 B/row; swizzle
// colbyte ^= ((row&7)<<4); inverse-swizzled global source (both-sides rule).
// MODE: 0 = bias+pq+relu, bf16 out; 1 = bias+pq, f32 out; 2 = raw f32 partial.
// ===========================================================================
#define SBAR()  do { __builtin_amdgcn_sched_barrier(0); __builtin_amdgcn_s_barrier(); \
                     __builtin_amdgcn_sched_barrier(0); } while (0)
#define VMCNT(N) asm volatile("s_waitcnt vmcnt(" #N ")" ::: "memory")

#define AB0 0
#define AB1 32768
#define BB0 65536
#define BB1 98304

// Stage 128 rows (half tile H) of SRC K-tile KT into LDS region DST
#define STG(SRC, KT, H, DST) do { \
    const char* _s = (SRC) + (long)((H) * 128) * Kb + (long)(KT) * 128; \
    char* _d = smem + (DST) + (H) * 16384 + wave * 1024; \
    __builtin_amdgcn_global_load_lds((const gu32*)_s, (lu32*)_d, 16, 0, 0); \
    __builtin_amdgcn_global_load_lds((const gu32*)(_s + 64 * Kb), (lu32*)(_d + 8192), 16, 0, 0); \
  } while (0)

#define LDA8(AOFF, FI, CK) (*(const short8*)(smem + (AOFF) + aRel + (FI) * 2048 + (CK)))
#define LDB8(BOFF, FJ, CK) (*(const short8*)(smem + (BOFF) + bRel + (FJ) * 2048 + (CK)))

// Fragment prefetch groups (write the persistent register sets)
#define PREF_ALO(BUF) do { _Pragma("unroll") \
    for (int f = 0; f < 4; ++f) { ar[f][0] = LDA8(BUF, f, ck0); ar[f][1] = LDA8(BUF, f, ck1); } \
  } while (0)
#define PREF_AHI(BUF) do { _Pragma("unroll") \
    for (int f = 0; f < 4; ++f) { ar[f][0] = LDA8(BUF, f + 4, ck0); ar[f][1] = LDA8(BUF, f + 4, ck1); } \
  } while (0)
#define PREF_B01(BUF) do { _Pragma("unroll") \
    for (int f = 0; f < 2; ++f) { b01[f][0] = LDB8(BUF, f, ck0); b01[f][1] = LDB8(BUF, f, ck1); } \
  } while (0)
#define PREF_B23(BUF) do { _Pragma("unroll") \
    for (int f = 0; f < 2; ++f) { b23[f][0] = LDB8(BUF, f + 2, ck0); b23[f][1] = LDB8(BUF, f + 2, ck1); } \
  } while (0)

// One quadrant: acc rows ACC0..ACC0+3, B set BS covering fj {FJ0, FJ0+1}
#define MQS(ACC0, BS, FJ0) do { \
    _Pragma("unroll") \
    for (int fi = 0; fi < 4; ++fi) { \
      _Pragma("unroll") \
      for (int fj = 0; fj < 2; ++fj) { \
        acc[(ACC0) + fi][(FJ0) + fj] = __builtin_amdgcn_mfma_f32_16x16x32_bf16( \
            ar[fi][0], BS[fj][0], acc[(ACC0) + fi][(FJ0) + fj], 0, 0, 0); \
        acc[(ACC0) + fi][(FJ0) + fj] = __builtin_amdgcn_mfma_f32_16x16x32_bf16( \
            ar[fi][1], BS[fj][1], acc[(ACC0) + fi][(FJ0) + fj], 0, 0, 0); \
      } \
    } \
  } while (0)

template <int MODE>
__global__ __launch_bounds__(512, 2) void gemm256_posit(
    const bf16* __restrict__ A, const bf16* __restrict__ B,
    const float* __restrict__ bias, void* __restrict__ out,
    int M, int N, int Kfull, int Kloop, int nbt, int cpx) {
  __shared__ __align__(1024) char smem[131072];

  const int tid  = threadIdx.x;
  const int lane = tid & 63;
  const int wave = tid >> 6;
  const int wr = wave >> 2;         // 0..1  (M half)
  const int wc = wave & 3;          // 0..3  (N quarter)

  // XCD-aware bijective swizzle (grid multiple of 8), then split-K decode
  const int flat = blockIdx.x;
  const int wgid = (flat & 7) * cpx + (flat >> 3);
  const int split = wgid / nbt;               // 0 unless split-K
  const int t = wgid - split * nbt;
  // 2D band decode: 16-row x 4-col bands (M=4096 -> 16 tile-rows always)
  const int trow = (t & 63) >> 2;
  const int tcol = ((t >> 6) << 2) | (t & 3);
  const long brow0 = (long)trow * 256;
  const long bcol0 = (long)tcol * 256;

  const long Kb = (long)Kfull * 2;            // row stride bytes
  const long splitoff = (long)split * Kloop * 2;

  // staging source (per-lane, inverse-swizzled)
  const int srow = tid >> 3;                                   // 0..63
  const int scb  = ((tid & 7) * 16) ^ (((tid >> 3) & 7) << 4);
  const char* srcA = (const char*)A + (brow0 + srow) * Kb + scb + splitoff;
  const char* srcB = (const char*)B + (bcol0 + srow) * Kb + scb + splitoff;

  // fragment read addressing (mfma_f32_16x16x32_bf16: row=lane&15, k=(lane>>4)*8)
  const int fr  = lane & 15;
  const int swz = (lane & 7) << 4;
  const int ck0 = (((lane >> 4) << 4)) ^ swz;
  const int ck1 = (64 + ((lane >> 4) << 4)) ^ swz;
  const int aRel = wr * 16384 + fr * 128;
  const int bRel = wc * 8192 + fr * 128;

  f32x4 acc[8][4] = {};
  short8 ar[4][2], b01[2][2], b23[2][2];

  const int nkt = Kloop >> 6;     // K tiles (power of 2)
  const int np  = nkt >> 1;

  // Prologue: B0,A0 then B1 (12 loads); vmcnt(4) completes tile 0; then
  // prefetch ph1's fragments (aLo + b01 of tile 0).
  STG(srcB, 0, 0, BB0); STG(srcB, 0, 1, BB0);
  STG(srcA, 0, 0, AB0); STG(srcA, 0, 1, AB0);
  STG(srcB, 1, 0, BB1); STG(srcB, 1, 1, BB1);
  VMCNT(4);
  SBAR();
  PREF_ALO(AB0); PREF_B01(BB0);
  __builtin_amdgcn_sched_barrier(0);

#pragma unroll 1
  for (int i = 0; i < np; ++i) {
    const int kA1 = 2 * i + 1;
    const int kS2 = (2 * i + 2) & (nkt - 1);  // tail wraps: harmless re-stage
    const int kS3 = (2 * i + 3) & (nkt - 1);

    // ph1: MFMA(aLo, b01) of T0; pre-read b23(T0); stage A(T0+1)h0 -> AB1
    PREF_B23(BB0);
    STG(srcA, kA1, 0, AB1);
    SBAR();
    __builtin_amdgcn_s_setprio(1); MQS(0, b01, 0); __builtin_amdgcn_s_setprio(0);
    SBAR();

    // ph2: MFMA(aLo, b23); post-read aHi(T0); stage A(T0+1)h1 -> AB1
    STG(srcA, kA1, 1, AB1);
    SBAR();
    __builtin_amdgcn_s_setprio(1); MQS(0, b23, 2); __builtin_amdgcn_s_setprio(0);
    PREF_AHI(AB0);
    SBAR();

    // ph3: MFMA(aHi, b01); stage B(T0+2)h0 -> BB0 (all BB0 reads drained pre-ph3)
    STG(srcB, kS2, 0, BB0);
    SBAR();
    __builtin_amdgcn_s_setprio(1); MQS(4, b01, 0); __builtin_amdgcn_s_setprio(0);
    SBAR();

    // ph4: MFMA(aHi, b23); stage B(T0+2)h1; vmcnt(4) -> T0+1 (AB1+BB1) ready;
    //      post-read aLo+b01 of T0+1
    STG(srcB, kS2, 1, BB0);
    VMCNT(4);
    SBAR();
    __builtin_amdgcn_s_setprio(1); MQS(4, b23, 2); __builtin_amdgcn_s_setprio(0);
    PREF_ALO(AB1); PREF_B01(BB1);
    SBAR();

    // ph5: MFMA(aLo, b01) of T0+1; pre-read b23(T0+1); stage A(T0+2)h0 -> AB0
    PREF_B23(BB1);
    STG(srcA, kS2, 0, AB0);
    SBAR();
    __builtin_amdgcn_s_setprio(1); MQS(0, b01, 0); __builtin_amdgcn_s_setprio(0);
    SBAR();

    // ph6: MFMA(aLo, b23); post-read aHi(T0+1); stage A(T0+2)h1 -> AB0
    STG(srcA, kS2, 1, AB0);
    SBAR();
    __builtin_amdgcn_s_setprio(1); MQS(0, b23, 2); __builtin_amdgcn_s_setprio(0);
    PREF_AHI(AB1);
    SBAR();

    // ph7: MFMA(aHi, b01); stage B(T0+3)h0 -> BB1
    STG(srcB, kS3, 0, BB1);
    SBAR();
    __builtin_amdgcn_s_setprio(1); MQS(4, b01, 0); __builtin_amdgcn_s_setprio(0);
    SBAR();

    // ph8: MFMA(aHi, b23); stage B(T0+3)h1; vmcnt(4) -> next T0 ready;
    //      post-read aLo+b01 of next T0
    STG(srcB, kS3, 1, BB1);
    VMCNT(4);
    SBAR();
    __builtin_amdgcn_s_setprio(1); MQS(4, b23, 2); __builtin_amdgcn_s_setprio(0);
    PREF_ALO(AB0); PREF_B01(BB0);
    SBAR();
  }
  asm volatile("s_waitcnt vmcnt(0) lgkmcnt(0)" ::: "memory");  // drain

  // Epilogue: C/D layout col=lane&15, row=(lane>>4)*4+q
  const int orow = (lane >> 4) * 4;
  const long row0 = brow0 + wr * 128;
  const long col0 = bcol0 + wc * 64;
  const long obase = (MODE == 2) ? (long)split * M * N : 0;
#pragma unroll
  for (int fj = 0; fj < 4; ++fj) {
    const long col = col0 + fj * 16 + fr;
    const float bv = (MODE == 2) ? 0.0f : posit_quant_f32(bias[col]);
#pragma unroll
    for (int fi = 0; fi < 8; ++fi) {
#pragma unroll
      for (int q = 0; q < 4; ++q) {
        float v = acc[fi][fj][q];
        if (MODE != 2) {
          v = posit_quant_f32(v + bv);
          if (MODE == 0) v = fmaxf(v, 0.0f);
        }
        const long idx = obase + (row0 + fi * 16 + orow + q) * (long)N + col;
        if (MODE == 0) ((bf16*)out)[idx] = __float2bfloat16(v);
        else           ((float*)out)[idx] = v;
      }
    }
  }
}

// ===========================================================================
// Round-1 128x128 m97-structure kernel (fallback for L2 if ws too small)
// ===========================================================================
#define GBM 128
#define GBN 128
#define GBK 32

__device__ __forceinline__ void gload_lds16(const void* g, void* l) {
  __builtin_amdgcn_global_load_lds((const gu32*)g, (lu32*)l, 16, 0, 0);
}

template <bool RELU, bool OUTBF16>
__global__ __launch_bounds__(256, 2) void gemm_bt_posit(
    const bf16* __restrict__ A, const bf16* __restrict__ B,
    const float* __restrict__ bias, void* __restrict__ out,
    int M, int N, int K) {
  __shared__ __align__(1024) bf16 sA[GBM][GBK];
  __shared__ __align__(1024) bf16 sB[GBN][GBK];

  const int tid = threadIdx.x;
  const int lane = tid & 63;
  const int wave = tid >> 6;
  const int wr = wave >> 1;
  const int wc = wave & 1;
  const long brow0 = (long)blockIdx.y * GBM;
  const long bcol0 = (long)blockIdx.x * GBN;

  const int srow = lane >> 2;
  const int scol = (lane & 3) * 8;
  const int seg0 = wave * 2;

  const bf16* gA0 = A + (brow0 + seg0 * 16 + srow) * (long)K + scol;
  const bf16* gA1 = A + (brow0 + seg0 * 16 + 16 + srow) * (long)K + scol;
  const bf16* gB0 = B + (bcol0 + seg0 * 16 + srow) * (long)K + scol;
  const bf16* gB1 = B + (bcol0 + seg0 * 16 + 16 + srow) * (long)K + scol;
  bf16* lA0 = (bf16*)sA + seg0 * 512;
  bf16* lA1 = lA0 + 512;
  bf16* lB0 = (bf16*)sB + seg0 * 512;
  bf16* lB1 = lB0 + 512;

  f32x4 acc[4][4] = {};
  const int fr = lane & 15;
  const int fk = (lane >> 4) * 8;

  for (int kt = 0; kt < K; kt += GBK) {
    __syncthreads();
    gload_lds16(gA0 + kt, lA0);
    gload_lds16(gA1 + kt, lA1);
    gload_lds16(gB0 + kt, lB0);
    gload_lds16(gB1 + kt, lB1);
    __syncthreads();

    short8 af[4], bfv[4];
#pragma unroll
    for (int i = 0; i < 4; ++i) af[i] = *(const short8*)&sA[wr * 64 + i * 16 + fr][fk];
#pragma unroll
    for (int j = 0; j < 4; ++j) bfv[j] = *(const short8*)&sB[wc * 64 + j * 16 + fr][fk];
#pragma unroll
    for (int i = 0; i < 4; ++i)
#pragma unroll
      for (int j = 0; j < 4; ++j)
        acc[i][j] = __builtin_amdgcn_mfma_f32_16x16x32_bf16(af[i], bfv[j], acc[i][j], 0, 0, 0);
  }

  const int orow = (lane >> 4) * 4;
  const long row0 = brow0 + wr * 64;
  const long col0 = bcol0 + wc * 64;
#pragma unroll
  for (int j = 0; j < 4; ++j) {
    const long col = col0 + j * 16 + fr;
    const float bv = posit_quant_f32(bias[col]);
#pragma unroll
    for (int i = 0; i < 4; ++i) {
#pragma unroll
      for (int q = 0; q < 4; ++q) {
        float v = posit_quant_f32(acc[i][j][q] + bv);
        if (RELU) v = fmaxf(v, 0.0f);
        const long idx = (row0 + i * 16 + orow + q) * (long)N + col;
        if (OUTBF16) ((bf16*)out)[idx] = __float2bfloat16(v);
        else         ((float*)out)[idx] = v;
      }
    }
  }
}

// ---------------------------------------------------------------------------
extern "C" void kernel_launch(void* const* d_in, const int* in_sizes, int n_in,
                              void* d_out, int out_size, void* d_ws, size_t ws_size,
                              hipStream_t stream) {
  const float* x  = (const float*)d_in[0];
  const float* W0 = (const float*)d_in[1];
  const float* b0 = (const float*)d_in[2];
  const float* W1 = (const float*)d_in[3];
  const float* b1 = (const float*)d_in[4];
  const float* W2 = (const float*)d_in[5];
  const float* b2 = (const float*)d_in[6];

  const int M = 4096, D0 = 2048, D1 = 8192, D2 = 8192, DO = 2048;

  char* ws = (char*)d_ws;
  size_t off = 0;
  auto alloc = [&](size_t bytes) {
    char* p = ws + off;
    off += (bytes + 255) & ~(size_t)255;
    return p;
  };
  bf16* xq  = (bf16*)alloc((size_t)M * D0 * 2);
  bf16* W0q = (bf16*)alloc((size_t)D1 * D0 * 2);
  bf16* W1q = (bf16*)alloc((size_t)D2 * D1 * 2);
  bf16* W2q = (bf16*)alloc((size_t)DO * D2 * 2);
  bf16* h0  = (bf16*)alloc((size_t)M * D1 * 2);
  bf16* h1  = (bf16*)alloc((size_t)M * D2 * 2);
  float* part = (float*)alloc((size_t)2 * M * DO * 4);   // split-K partials
  const bool splitk = (off <= ws_size);
  (void)in_sizes; (void)n_in; (void)out_size;

  // Single launch quantizing x, W0, W1, W2 -> bf16 posit values
  {
    long q0 = (long)M * D0 / 4;
    long q1 = q0 + (long)D1 * D0 / 4;
    long q2 = q1 + (long)D2 * D1 / 4;
    long q3 = q2 + (long)DO * D2 / 4;
    kquant_all<<<2048, 256, 0, stream>>>(x, xq, W0, W0q, W1, W1q, W2, W2q,
                                         q0, q1, q2, q3);
  }

  // L0: h0 = relu(pq(xq @ W0q^T + pq(b0)))   M=4096 N=8192 K=2048
  {
    int nbt = (D1 / 256) * (M / 256), nwg = nbt;
    gemm256_posit<0><<<dim3(nwg), dim3(512), 0, stream>>>(
        xq, W0q, b0, h0, M, D1, D0, D0, nbt, nwg / 8);
  }
  // L1: h1 = relu(pq(h0 @ W1q^T + pq(b1)))   M=4096 N=8192 K=8192
  {
    int nbt = (D2 / 256) * (M / 256), nwg = nbt;
    gemm256_posit<0><<<dim3(nwg), dim3(512), 0, stream>>>(
        h0, W1q, b1, h1, M, D2, D1, D1, nbt, nwg / 8);
  }
  // L2: out = pq(h1 @ W2q^T + pq(b2))  f32   M=4096 N=2048 K=8192
  if (splitk) {
    int nbt = (DO / 256) * (M / 256);      // 128 tiles per split
    int nwg = nbt * 2;                     // 256 blocks, full occupancy
    gemm256_posit<2><<<dim3(nwg), dim3(512), 0, stream>>>(
        h1, W2q, nullptr, part, M, DO, D2, D2 / 2, nbt, nwg / 8);
    long n4 = (long)M * DO / 4;
    kcombine<<<2048, 256, 0, stream>>>(part, b2, (float*)d_out, n4,
                                       (long)M * DO, DO / 4 - 1);
  } else {
    gemm_bt_posit<false, false><<<dim3(DO / GBN, M / GBM), dim3(256), 0, stream>>>(
        h1, W2q, b2, (float*)d_out, M, DO, D2);
  }
}